// Round 16
// baseline (1029.542 us; speedup 1.0000x reference)
//
#include <hip/hip_runtime.h>
#include <math.h>
#include <stdint.h>

typedef unsigned short u16;
typedef _Float16 f16;
typedef __attribute__((ext_vector_type(8))) _Float16 f16x8;
typedef __attribute__((ext_vector_type(8))) short s16x8;
typedef __attribute__((ext_vector_type(4))) float f32x4;
typedef __attribute__((ext_vector_type(4))) unsigned short u16x4;

#define DEV static __device__ __forceinline__

#define MFMA16(a, b, c) __builtin_amdgcn_mfma_f32_16x16x32_f16((a), (b), (c), 0, 0, 0)

// split f32 into hi+lo fp16 (residual rel ~2^-22)
DEV void split2(float v, u16& hi, u16& lo) {
  f16 h = (f16)v;
  f16 l = (f16)(v - (float)h);
  hi = __builtin_bit_cast(u16, h);
  lo = __builtin_bit_cast(u16, l);
}
DEV u16 f2h(float v) { f16 h = (f16)v; return __builtin_bit_cast(u16, h); }
DEV float h2f(u16 u) { f16 h = __builtin_bit_cast(f16, u); return (float)h; }

DEV void gload16(const void* gp, const void* lp) {
  typedef const __attribute__((address_space(1))) unsigned GU;
  typedef __attribute__((address_space(3))) unsigned LU;
  GU* g = (GU*)(uintptr_t)gp;
  LU* l = (LU*)(unsigned)(uintptr_t)lp;
  __builtin_amdgcn_global_load_lds(g, l, 16, 0, 0);
}

// P-plane LDS swizzle: write q-rows conflict-free, read rows 2-way
DEV int swzP(int q) { return ((q & 3) << 4) ^ (((q >> 2) & 3) << 5); }

// GEMM tile chunk swizzle: 16B-chunk c of row r stored at chunk c^((r>>1)&3).
// Staged via pre-swizzled GLOBAL source col (gload_lds dest stays linear);
// read via XOR on the k-chunk index. 8-way -> 2-way bank aliasing (free).

// ---------------------------------------------------------------------------
// Emulated-f32 GEMM: C = (Ah+Al)*(Bh+Bl)^T, 3-term MFMA (ll dropped, ~1e-7).
// 128x128 tile, BK=32, 8 waves. Double-buffered prefetch K-loop.
// 1D grid, XCD-chunked by ROW (A-panel L2-resident); grid = 32*nColT.
// ---------------------------------------------------------------------------
enum { EPI3_SPLIT = 0, EPI3_RESID = 1 };

template <int EPI>
__global__ __launch_bounds__(512, 4)
void gemm3(const u16* __restrict__ Ah, const u16* __restrict__ Al,
           const u16* __restrict__ Bh, const u16* __restrict__ Bl,
           int nColT, int K, int ldC,
           u16* __restrict__ outh, u16* __restrict__ outl,
           float* __restrict__ outf, const float* __restrict__ resid)
{
  __shared__ alignas(16) u16 sAh[2][128 * 32], sAl[2][128 * 32];
  __shared__ alignas(16) u16 sBh[2][128 * 32], sBl[2][128 * 32];
  const int L = blockIdx.x;
  const int s = L >> 3;
  const int rt = (L & 7) * 4 + s / nColT;    // 4 row-tiles per XCD (32 total)
  const int ct = s % nColT;
  const int tid = threadIdx.x;
  const int wave = tid >> 6, lane = tid & 63;
  const int wr = wave >> 2, wc = wave & 3;      // 2x4 waves, 64x32 tile each
  const int li = lane & 15, g = lane >> 4;
  const long row0 = (long)rt * 128;
  const int col0 = ct * 128;

  const int srow = tid >> 2;                    // 0..127
  const int scol = ((tid & 3) ^ ((tid >> 3) & 3)) * 8;   // swizzled source chunk
  const long arow = (row0 + srow) * (long)K + scol;
  const long brow = ((long)col0 + srow) * (long)K + scol;
  const u16 *gAh = Ah + arow, *gAl = Al + arow;
  const u16 *gBh = Bh + brow, *gBl = Bl + brow;
  const int wbase = wave * 512;                 // wave-uniform LDS base (elems)

  const f32x4 fz = {0.f, 0.f, 0.f, 0.f};
  f32x4 acc[4][2];
#pragma unroll
  for (int m = 0; m < 4; m++)
#pragma unroll
    for (int n = 0; n < 2; n++) acc[m][n] = fz;

  const int aoff = (wr * 64 + li) * 32 + (g ^ ((li >> 1) & 3)) * 8;
  const int boff = (wc * 32 + li) * 32 + (g ^ ((li >> 1) & 3)) * 8;

  // prologue: stage k0=0 into buf 0
  gload16(gAh, &sAh[0][wbase]);
  gload16(gAl, &sAl[0][wbase]);
  gload16(gBh, &sBh[0][wbase]);
  gload16(gBl, &sBl[0][wbase]);

  int cur = 0;
  for (int k0 = 0; k0 < K; k0 += 32, cur ^= 1) {
    __syncthreads();   // buf[cur] staged (implicit vmcnt drain); buf[nxt] free
    const int nxt = cur ^ 1;
    if (k0 + 32 < K) {
      gload16(gAh + k0 + 32, &sAh[nxt][wbase]);
      gload16(gAl + k0 + 32, &sAl[nxt][wbase]);
      gload16(gBh + k0 + 32, &sBh[nxt][wbase]);
      gload16(gBl + k0 + 32, &sBl[nxt][wbase]);
    }
    f16x8 ah[4], al4[4], bh[2], bl4[2];
#pragma unroll
    for (int m = 0; m < 4; m++) {
      ah[m] = *(const f16x8*)(&sAh[cur][aoff + m * 512]);
      al4[m] = *(const f16x8*)(&sAl[cur][aoff + m * 512]);
    }
#pragma unroll
    for (int n = 0; n < 2; n++) {
      bh[n] = *(const f16x8*)(&sBh[cur][boff + n * 512]);
      bl4[n] = *(const f16x8*)(&sBl[cur][boff + n * 512]);
    }
#pragma unroll
    for (int m = 0; m < 4; m++)
#pragma unroll
      for (int n = 0; n < 2; n++) {
        f32x4 t = acc[m][n];
        t = MFMA16(al4[m], bh[n], t);
        t = MFMA16(ah[m], bl4[n], t);
        t = MFMA16(ah[m], bh[n], t);
        acc[m][n] = t;
      }
  }

#pragma unroll
  for (int m = 0; m < 4; m++)
#pragma unroll
    for (int n = 0; n < 2; n++) {
      const int col = col0 + wc * 32 + n * 16 + li;
#pragma unroll
      for (int r = 0; r < 4; r++) {
        const long row = row0 + wr * 64 + m * 16 + g * 4 + r;
        const long idx = row * ldC + col;
        const float v = acc[m][n][r];
        if constexpr (EPI == EPI3_SPLIT) {
          u16 hi, lo; split2(v, hi, lo);
          outh[idx] = hi; outl[idx] = lo;
        } else {
          outf[idx] = resid[idx] + v;
        }
      }
    }
}

// ---------------------------------------------------------------------------
// V transpose: [4096 rows=(b,key)][ld 3072] (cols h*64+dh) -> Vt[(b*16+h)*64+dh][1024 keys]
// ---------------------------------------------------------------------------
__global__ __launch_bounds__(256)
void vtrans(const u16* __restrict__ Vh, const u16* __restrict__ Vl,
            u16* __restrict__ Th, u16* __restrict__ Tl)
{
  __shared__ u16 t0[64][80];
  __shared__ u16 t1[64][80];
  const int kb = blockIdx.x, h = blockIdx.y, b = blockIdx.z;
  const int tid = threadIdx.x;
  const int r = tid >> 2;        // 0..63 key row
  const int c = tid & 3;         // chunk
  const long srow = ((long)b * 1024 + kb * 64 + r) * 3072 + h * 64;
  s16x8 a0 = *(const s16x8*)(Vh + srow + c * 8);
  s16x8 a1 = *(const s16x8*)(Vh + srow + c * 8 + 32);
  s16x8 b0 = *(const s16x8*)(Vl + srow + c * 8);
  s16x8 b1 = *(const s16x8*)(Vl + srow + c * 8 + 32);
#pragma unroll
  for (int j = 0; j < 8; j++) {
    t0[c * 8 + j][r]      = (u16)(short)a0[j];
    t0[c * 8 + 32 + j][r] = (u16)(short)a1[j];
    t1[c * 8 + j][r]      = (u16)(short)b0[j];
    t1[c * 8 + 32 + j][r] = (u16)(short)b1[j];
  }
  __syncthreads();
  const int dh = tid >> 2;
  const long drow = ((long)(b * 16 + h) * 64 + dh) * 1024 + kb * 64;
  s16x8 o0, o1;
#pragma unroll
  for (int j = 0; j < 8; j++) {
    o0[j] = (short)t0[dh][c * 8 + j];
    o1[j] = (short)t0[dh][c * 8 + 32 + j];
  }
  *(s16x8*)(Th + drow + c * 8) = o0;
  *(s16x8*)(Th + drow + c * 8 + 32) = o1;
#pragma unroll
  for (int j = 0; j < 8; j++) {
    o0[j] = (short)t1[dh][c * 8 + j];
    o1[j] = (short)t1[dh][c * 8 + 32 + j];
  }
  *(s16x8*)(Tl + drow + c * 8) = o0;
  *(s16x8*)(Tl + drow + c * 8 + 32) = o1;
}

// ---------------------------------------------------------------------------
// Flash attention, emulated-f32 (3-term MFMA). V pre-transposed.
// QBLK=128, 8 waves x 16 q-rows. XCD-chunked grid (512).
// Row-sum l computed via ones-MFMA fused with PV (no shfl-sum).
// ---------------------------------------------------------------------------
__global__ __launch_bounds__(512, 4)
void attn3(const u16* __restrict__ Qh, const u16* __restrict__ Ql,
           const u16* __restrict__ Kbh, const u16* __restrict__ Kbl,
           const u16* __restrict__ Vth, const u16* __restrict__ Vtl,
           u16* __restrict__ AOh, u16* __restrict__ AOl)
{
  __shared__ alignas(16) u16 lKh[64 * 64], lKl[64 * 64];
  __shared__ alignas(16) u16 lVh[64 * 64], lVl[64 * 64];   // [dh][key], swizzled
  __shared__ alignas(16) u16 lPh[8 * 16 * 64], lPl[8 * 16 * 64];
  const int L = blockIdx.x;
  const int idx = L >> 3;
  const int qt = idx & 7;                  // q-tile contiguous within XCD
  const int bhp = (L & 7) * 8 + (idx >> 3);
  const int b = bhp >> 4, h = bhp & 15;
  const int tid = threadIdx.x;
  const int wave = tid >> 6, lane = tid & 63;
  const int li = lane & 15, g = lane >> 4;
  const int bh = b * 16 + h;
  const int LD = 3072;

  const long qrow0 = (long)b * 1024 + qt * 128 + wave * 16;
  f16x8 qfh[2], qfl[2];
#pragma unroll
  for (int kk = 0; kk < 2; kk++) {
    const long qoff = (qrow0 + li) * LD + h * 64 + kk * 32 + g * 8;
    qfh[kk] = *(const f16x8*)(Qh + qoff);
    qfl[kk] = *(const f16x8*)(Ql + qoff);
  }

  const f32x4 fz = {0.f, 0.f, 0.f, 0.f};
  f16x8 one8;
#pragma unroll
  for (int j = 0; j < 8; j++) one8[j] = (f16)1.f;
  float m_run[4];
  f32x4 lsum = fz;
  f32x4 oacc[4];
#pragma unroll
  for (int r = 0; r < 4; r++) m_run[r] = -INFINITY;
#pragma unroll
  for (int d = 0; d < 4; d++) oacc[d] = fz;

  char* cKh = (char*)lKh; char* cKl = (char*)lKl;
  char* cVh = (char*)lVh; char* cVl = (char*)lVl;
  char* cPh = (char*)lPh + wave * 2048;
  char* cPl = (char*)lPl + wave * 2048;

  const int kr = tid >> 3;              // 0..63
  const int kce = (tid & 7) * 8;
  const u16* kbase_h = Kbh + ((long)b * 1024 + kr) * LD + h * 64 + kce;
  const u16* kbase_l = Kbl + ((long)b * 1024 + kr) * LD + h * 64 + kce;
  const u16* vbase_h = Vth + ((long)bh * 64 + kr) * 1024 + kce;
  const u16* vbase_l = Vtl + ((long)bh * 64 + kr) * 1024 + kce;
  const int sdst = kr * 128 + ((kce * 2) ^ ((kr & 7) << 4));

  s16x8 rkh, rkl, rvh, rvl;
#define LOADT(t)                                                   \
  {                                                                \
    const long ko = (long)(t) * 64 * LD;                           \
    const int vo = (t) * 64;                                       \
    rkh = *(const s16x8*)(kbase_h + ko);                           \
    rkl = *(const s16x8*)(kbase_l + ko);                           \
    rvh = *(const s16x8*)(vbase_h + vo);                           \
    rvl = *(const s16x8*)(vbase_l + vo);                           \
  }

  LOADT(0);

  for (int t = 0; t < 16; ++t) {
    __syncthreads();
    *(s16x8*)(cKh + sdst) = rkh;
    *(s16x8*)(cKl + sdst) = rkl;
    *(s16x8*)(cVh + sdst) = rvh;
    *(s16x8*)(cVl + sdst) = rvl;
    if (t < 15) LOADT(t + 1);
    __syncthreads();

    f32x4 s[4];
#pragma unroll
    for (int cb = 0; cb < 4; cb++) {
      f32x4 tt = fz;
      const int key = cb * 16 + li;
#pragma unroll
      for (int kk = 0; kk < 2; kk++) {
        const int off = key * 128 + (((kk * 32 + g * 8) * 2) ^ ((key & 7) << 4));
        f16x8 fh = *(const f16x8*)(cKh + off);
        f16x8 fl = *(const f16x8*)(cKl + off);
        tt = MFMA16(qfl[kk], fh, tt);
        tt = MFMA16(qfh[kk], fl, tt);
        tt = MFMA16(qfh[kk], fh, tt);
      }
      s[cb] = tt;
    }
#pragma unroll
    for (int cb = 0; cb < 4; cb++)
#pragma unroll
      for (int r = 0; r < 4; r++) s[cb][r] *= 0.125f;

    // online softmax: max via shfl; sum deferred to ones-MFMA in PV
#pragma unroll
    for (int r = 0; r < 4; r++) {
      float mx = fmaxf(fmaxf(s[0][r], s[1][r]), fmaxf(s[2][r], s[3][r]));
      mx = fmaxf(mx, __shfl_xor(mx, 1));
      mx = fmaxf(mx, __shfl_xor(mx, 2));
      mx = fmaxf(mx, __shfl_xor(mx, 4));
      mx = fmaxf(mx, __shfl_xor(mx, 8));
      float mnew = fmaxf(m_run[r], mx);
      float sc = __expf(m_run[r] - mnew);
      m_run[r] = mnew;
#pragma unroll
      for (int cb = 0; cb < 4; cb++) s[cb][r] = __expf(s[cb][r] - mnew);
      lsum[r] *= sc;
#pragma unroll
      for (int d = 0; d < 4; d++) oacc[d][r] *= sc;
    }

#pragma unroll
    for (int cb = 0; cb < 4; cb++)
#pragma unroll
      for (int r = 0; r < 4; r++) {
        const int q = g * 4 + r;
        const int key = cb * 16 + li;
        const int off = q * 128 + ((key * 2) ^ swzP(q));
        u16 hi, lo; split2(s[cb][r], hi, lo);
        *(u16*)(cPh + off) = hi;
        *(u16*)(cPl + off) = lo;
      }

#pragma unroll
    for (int kk = 0; kk < 2; kk++) {
      const int kbyte = (kk * 32 + g * 8) * 2;
      const int poff = li * 128 + (kbyte ^ swzP(li));
      f16x8 pfh = *(const f16x8*)(cPh + poff);
      f16x8 pfl = *(const f16x8*)(cPl + poff);
#pragma unroll
      for (int d = 0; d < 4; d++) {
        const int dh = d * 16 + li;
        const int voff = dh * 128 + (kbyte ^ ((dh & 7) << 4));
        f16x8 vfh = *(const f16x8*)(cVh + voff);
        f16x8 vfl = *(const f16x8*)(cVl + voff);
        f32x4 tacc = oacc[d];
        tacc = MFMA16(pfl, vfh, tacc);
        tacc = MFMA16(pfh, vfl, tacc);
        tacc = MFMA16(pfh, vfh, tacc);
        oacc[d] = tacc;
      }
      // row-sum of P via ones-B MFMA (every lane's r-elem = rowsum of q=g*4+r)
      lsum = MFMA16(pfh, one8, lsum);
      lsum = MFMA16(pfl, one8, lsum);
    }
  }
#undef LOADT

#pragma unroll
  for (int d = 0; d < 4; d++)
#pragma unroll
    for (int r = 0; r < 4; r++) {
      const long row = qrow0 + g * 4 + r;
      const int col = h * 64 + d * 16 + li;
      u16 hi, lo; split2(oacc[d][r] / lsum[r], hi, lo);
      AOh[row * 1024 + col] = hi;
      AOl[row * 1024 + col] = lo;
    }
}

// ---------------------------------------------------------------------------
// LayerNorm over D=1024 (one block/token) -> hi/lo fp16; optional f32 gate logits.
// ---------------------------------------------------------------------------
template <bool GATE>
__global__ __launch_bounds__(256)
void ln_kernel(const float* __restrict__ x, const float* __restrict__ gam,
               const float* __restrict__ bet, u16* __restrict__ hh,
               u16* __restrict__ hl,
               const float* __restrict__ Wg, float* __restrict__ glog)
{
  const int row = blockIdx.x;
  const int tid = threadIdx.x;
  const int wave = tid >> 6, lane = tid & 63;
  const float* xr = x + (long)row * 1024;
  float4 v = *(const float4*)(xr + tid * 4);
  float s = v.x + v.y + v.z + v.w;
  float s2 = v.x * v.x + v.y * v.y + v.z * v.z + v.w * v.w;
#pragma unroll
  for (int m = 1; m < 64; m <<= 1) { s += __shfl_xor(s, m); s2 += __shfl_xor(s2, m); }
  __shared__ float red1[4], red2[4];
  if (lane == 0) { red1[wave] = s; red2[wave] = s2; }
  __syncthreads();
  float S = red1[0] + red1[1] + red1[2] + red1[3];
  float S2 = red2[0] + red2[1] + red2[2] + red2[3];
  float mean = S * (1.f / 1024.f);
  float var = S2 * (1.f / 1024.f) - mean * mean;
  float rstd = 1.f / sqrtf(var + 1e-5f);
  const int c = tid * 4;
  float hv[4];
  hv[0] = (v.x - mean) * rstd * gam[c + 0] + bet[c + 0];
  hv[1] = (v.y - mean) * rstd * gam[c + 1] + bet[c + 1];
  hv[2] = (v.z - mean) * rstd * gam[c + 2] + bet[c + 2];
  hv[3] = (v.w - mean) * rstd * gam[c + 3] + bet[c + 3];
  u16x4 oh, ol;
#pragma unroll
  for (int j = 0; j < 4; j++) {
    u16 hi, lo; split2(hv[j], hi, lo);
    oh[j] = hi; ol[j] = lo;
  }
  *(u16x4*)(hh + (long)row * 1024 + c) = oh;
  *(u16x4*)(hl + (long)row * 1024 + c) = ol;

  if constexpr (GATE) {
    float pe[4];
#pragma unroll
    for (int e = 0; e < 4; e++) {
      const float* wr_ = Wg + e * 1024 + c;
      pe[e] = hv[0] * wr_[0] + hv[1] * wr_[1] + hv[2] * wr_[2] + hv[3] * wr_[3];
    }
#pragma unroll
    for (int e = 0; e < 4; e++)
#pragma unroll
      for (int m = 1; m < 64; m <<= 1) pe[e] += __shfl_xor(pe[e], m);
    __shared__ float gred[4][4];
    if (lane == 0) {
#pragma unroll
      for (int e = 0; e < 4; e++) gred[wave][e] = pe[e];
    }
    __syncthreads();
    if (tid < 4)
      glog[(long)row * 4 + tid] = gred[0][tid] + gred[1][tid] + gred[2][tid] + gred[3][tid];
  }
}

// ---------------------------------------------------------------------------
// Routing: top-2 + deterministic compaction (128-padded per-expert lists) + aux.
// ---------------------------------------------------------------------------
__global__ __launch_bounds__(256)
void route_kernel(const float* __restrict__ glog,
                  int* __restrict__ tlist, float* __restrict__ wrow,
                  int4* __restrict__ meta, float2* __restrict__ wts,
                  int* __restrict__ scanMeta, float* __restrict__ outAux)
{
  const int tid = threadIdx.x;
  const int lane = tid & 63, wave = tid >> 6;
  __shared__ int scn[4][256];
  __shared__ int sTot[4];
  __shared__ int sBase[4];
  __shared__ float sred[4][8];

  for (int r = tid; r < 8704; r += 256) { tlist[r] = 0; wrow[r] = 0.f; }

  int myCnt[4] = {0, 0, 0, 0};
  float imp[4] = {0.f, 0.f, 0.f, 0.f}, ld[4] = {0.f, 0.f, 0.f, 0.f};
  unsigned char e1s[16], e2s[16];
  float w1s[16], w2s[16];
#pragma unroll 1
  for (int j = 0; j < 16; j++) {
    const int t = tid * 16 + j;
    float l[4];
#pragma unroll
    for (int e = 0; e < 4; e++) l[e] = glog[t * 4 + e];
    int e1 = 0; float bv = l[0];
#pragma unroll
    for (int e = 1; e < 4; e++) if (l[e] > bv) { bv = l[e]; e1 = e; }
    int e2 = -1; float bv2 = -INFINITY;
#pragma unroll
    for (int e = 0; e < 4; e++) if (e != e1 && l[e] > bv2) { bv2 = l[e]; e2 = e; }
    float wq = expf(bv2 - bv);
    float w1 = 1.f / (1.f + wq), w2 = wq / (1.f + wq);
    float ps = 0.f, pv[4];
#pragma unroll
    for (int e = 0; e < 4; e++) { pv[e] = expf(l[e] - bv); ps += pv[e]; }
    float inv = 1.f / ps;
#pragma unroll
    for (int e = 0; e < 4; e++) imp[e] += pv[e] * inv;
    ld[e1] += 1.f; ld[e2] += 1.f;
    myCnt[e1]++; myCnt[e2]++;
    e1s[j] = (unsigned char)e1; e2s[j] = (unsigned char)e2;
    w1s[j] = w1; w2s[j] = w2;
  }
#pragma unroll
  for (int e = 0; e < 4; e++) scn[e][tid] = myCnt[e];
  __syncthreads();

  if (wave < 4) {
    int carry = 0;
    for (int seg = 0; seg < 4; seg++) {
      int v = scn[wave][seg * 64 + lane];
      const int orig = v;
#pragma unroll
      for (int d = 1; d < 64; d <<= 1) { int o = __shfl_up(v, d); if (lane >= d) v += o; }
      scn[wave][seg * 64 + lane] = carry + v - orig;
      carry += __shfl(v, 63);
    }
    if (lane == 0) sTot[wave] = carry;
  }
  __syncthreads();

  if (tid == 0) {
    int base = 0;
    for (int e = 0; e < 4; e++) {
      const int c = sTot[e];
      const int cap = (c + 127) & ~127;
      sBase[e] = base;
      const int t0 = base >> 7, t1 = (base + cap) >> 7;
      for (int i = t0; i < t1; i++) scanMeta[1 + i] = e;
      base += cap;
    }
    scanMeta[0] = base >> 7;
  }
  __syncthreads();

  int off[4];
#pragma unroll
  for (int e = 0; e < 4; e++) off[e] = sBase[e] + scn[e][tid];
#pragma unroll 1
  for (int j = 0; j < 16; j++) {
    const int t = tid * 16 + j;
    const int e1 = e1s[j], e2 = e2s[j];
    const int p1 = off[e1]++;
    const int p2 = off[e2]++;
    tlist[p1] = t; wrow[p1] = w1s[j];
    tlist[p2] = t; wrow[p2] = w2s[j];
    int4 m; m.x = p1; m.y = p2; m.z = e1; m.w = e2;
    meta[t] = m;
    float2 w; w.x = w1s[j]; w.y = w2s[j];
    wts[t] = w;
  }

#pragma unroll
  for (int e = 0; e < 4; e++) {
#pragma unroll
    for (int d = 1; d < 64; d <<= 1) {
      imp[e] += __shfl_xor(imp[e], d);
      ld[e] += __shfl_xor(ld[e], d);
    }
  }
  if (lane == 0) {
#pragma unroll
    for (int e = 0; e < 4; e++) { sred[wave][e] = imp[e]; sred[wave][4 + e] = ld[e]; }
  }
  __syncthreads();
  if (tid == 0) {
    float a = 0.f;
    for (int e = 0; e < 4; e++) {
      float im = sred[0][e] + sred[1][e] + sred[2][e] + sred[3][e];
      float lo = sred[0][4 + e] + sred[1][4 + e] + sred[2][4 + e] + sred[3][4 + e];
      a += (lo * (1.f / 4096.f)) * (im * (1.f / 4096.f));
    }
    outAux[0] = 0.01f * 4.f * a;
  }
}

// ---------------------------------------------------------------------------
// Sparse MoE up-proj: 128x256 tile, 512 thr / 8 waves (2x4, 64x64 wave tile).
// ROW-chunked XCD grid 1088 = 8 * 136. LDS 48KB -> 3 blocks/CU via (512,6).
// Dbuf prefetch K-loop.
// ---------------------------------------------------------------------------
__global__ __launch_bounds__(512, 6)
void gemm_up(const u16* __restrict__ A, const u16* __restrict__ w1h,
             const float* __restrict__ b1, const int* __restrict__ tlist,
             const float* __restrict__ wrow, const int* __restrict__ scanMeta,
             u16* __restrict__ hid)
{
  const int L = blockIdx.x;
  const int gg = (L & 7) * 136 + (L >> 3);
  const int rt = gg >> 4, ct = gg & 15;
  if (rt >= scanMeta[0]) return;
  const int e = scanMeta[1 + rt];
  __shared__ alignas(16) u16 lA[2][128 * 32];
  __shared__ alignas(16) u16 lB[2][256 * 32];
  const int tid = threadIdx.x;
  const int wave = tid >> 6, lane = tid & 63;
  const int wr = wave >> 2, wcn = wave & 3;   // 2x4 waves, 64x64 wave tile
  const int li = lane & 15, g = lane >> 4;
  const int row0 = rt * 128;
  const int col0 = ct * 256;

  const int srow = tid >> 2;                  // 0..127
  const int scol = ((tid & 3) ^ ((tid >> 3) & 3)) * 8;   // swizzled source chunk
  const long t1 = tlist[row0 + srow];
  const u16* gA1 = A + t1 * 1024 + scol;
  const u16* gB1 = w1h + (size_t)e * 4194304 +
                   ((size_t)(col0 + srow)) * 1024 + scol;
  const u16* gB2 = gB1 + (size_t)128 * 1024;
  const int wb = wave * 512;                  // wave-uniform LDS base (elems)

  const f32x4 fz = {0.f, 0.f, 0.f, 0.f};
  f32x4 acc[4][4];
#pragma unroll
  for (int m = 0; m < 4; m++)
#pragma unroll
    for (int n = 0; n < 4; n++) acc[m][n] = fz;

  const int aoff = (wr * 64 + li) * 32 + (g ^ ((li >> 1) & 3)) * 8;
  const int boff = (wcn * 64 + li) * 32 + (g ^ ((li >> 1) & 3)) * 8;

  // prologue
  gload16(gA1, &lA[0][wb]);
  gload16(gB1, &lB[0][wb]);
  gload16(gB2, &lB[0][4096 + wb]);

  int cur = 0;
  for (int k0 = 0; k0 < 1024; k0 += 32, cur ^= 1) {
    __syncthreads();
    const int nxt = cur ^ 1;
    if (k0 + 32 < 1024) {
      gload16(gA1 + k0 + 32, &lA[nxt][wb]);
      gload16(gB1 + k0 + 32, &lB[nxt][wb]);
      gload16(gB2 + k0 + 32, &lB[nxt][4096 + wb]);
    }
    f16x8 af[4], bfr[4];
#pragma unroll
    for (int m = 0; m < 4; m++) af[m] = *(const f16x8*)(&lA[cur][aoff + m * 512]);
#pragma unroll
    for (int n = 0; n < 4; n++) bfr[n] = *(const f16x8*)(&lB[cur][boff + n * 512]);
#pragma unroll
    for (int m = 0; m < 4; m++)
#pragma unroll
      for (int n = 0; n < 4; n++)
        acc[m][n] = MFMA16(af[m], bfr[n], acc[m][n]);
  }

#pragma unroll
  for (int m = 0; m < 4; m++)
#pragma unroll
    for (int n = 0; n < 4; n++) {
      const int col = col0 + wcn * 64 + n * 16 + li;
#pragma unroll
      for (int r = 0; r < 4; r++) {
        const int row = row0 + wr * 64 + m * 16 + g * 4 + r;
        const float coef = wrow[row];
        float tv = acc[m][n][r] + b1[e * 4096 + col];
        float z = 1.59576912f * tv * (1.f + 0.044715f * tv * tv);
        float ge = tv / (1.f + __expf(-z));
        hid[(size_t)row * 4096 + col] = f2h(coef * ge);
      }
    }
}

// ---------------------------------------------------------------------------
// Sparse MoE down-proj -> fp16 partials. ROW-chunked XCD mapping (r6-proven).
// LDS 32KB + VGPR 36 -> 4 blocks/CU via (512,8).
// ---------------------------------------------------------------------------
__global__ __launch_bounds__(512, 8)
void gemm_down(const u16* __restrict__ hid, const u16* __restrict__ w2h,
               const int* __restrict__ scanMeta, u16* __restrict__ part)
{
  const int L = blockIdx.x;
  const int gg = (L & 7) * 68 + (L >> 3);
  const int rt = gg >> 3, cc = gg & 7;
  if (rt >= scanMeta[0]) return;
  const int e = scanMeta[1 + rt];
  __shared__ alignas(16) u16 lA[2][128 * 32];
  __shared__ alignas(16) u16 lB[2][128 * 32];
  const int tid = threadIdx.x;
  const int wave = tid >> 6, lane = tid & 63;
  const int wr = wave >> 2, wc = wave & 3;
  const int li = lane & 15, g = lane >> 4;
  const int row0 = rt * 128;
  const int col0 = cc * 128;

  const int srow = tid >> 2;           // 0..127
  const int scol = ((tid & 3) ^ ((tid >> 3) & 3)) * 8;   // swizzled source chunk
  const u16* gA = hid + ((size_t)(row0 + srow)) * 4096 + scol;
  const u16* gB = w2h + (size_t)e * 4194304 +
                  ((size_t)(col0 + srow)) * 4096 + scol;
  const int wbase = wave * 512;

  const f32x4 fz = {0.f, 0.f, 0.f, 0.f};
  f32x4 acc[4][2];
#pragma unroll
  for (int m = 0; m < 4; m++)
#pragma unroll
    for (int n = 0; n < 2; n++) acc[m][n] = fz;

  const int aoff = (wr * 64 + li) * 32 + (g ^ ((li >> 1) & 3)) * 8;
  const int boff = (wc * 32 + li) * 32 + (g ^ ((li >> 1) & 3)) * 8;

  // prologue
  gload16(gA, &lA[0][wbase]);
  gload16(gB, &lB[0][wbase]);

  int cur = 0;
  for (int k0 = 0; k0 < 4096; k0 += 32, cur ^= 1) {
    __syncthreads();
    const int nxt = cur ^ 1;
    if (k0 + 32 < 4096) {
      gload16(gA + k0 + 32, &lA[nxt][wbase]);
      gload16(gB + k0 + 32, &lB[nxt][wbase]);
    }
    f16x8 af[4], bfr[2];
#pragma unroll
    for (int m = 0; m < 4; m++) af[m] = *(const f16x8*)(&lA[cur][aoff + m * 512]);
#pragma unroll
    for (int n = 0; n < 2; n++) bfr[n] = *(const f16x8*)(&lB[cur][boff + n * 512]);
#pragma unroll
    for (int m = 0; m < 4; m++)
#pragma unroll
      for (int n = 0; n < 2; n++)
        acc[m][n] = MFMA16(af[m], bfr[n], acc[m][n]);
  }

#pragma unroll
  for (int m = 0; m < 4; m++)
#pragma unroll
    for (int n = 0; n < 2; n++) {
      const int col = col0 + wc * 32 + n * 16 + li;
#pragma unroll
      for (int r = 0; r < 4; r++) {
        const int row = row0 + wr * 64 + m * 16 + g * 4 + r;
        part[(size_t)row * 1024 + col] = f2h(acc[m][n][r]);
      }
    }
}

// ---------------------------------------------------------------------------
// Merge: out = xw + part[p1] + part[p2] + w1*b2[e1] + w2*b2[e2]
// ---------------------------------------------------------------------------
__global__ __launch_bounds__(256)
void merge_kernel(const float* __restrict__ xw, const u16* __restrict__ part,
                  const int4* __restrict__ meta, const float2* __restrict__ wts,
                  const float* __restrict__ b2, float* __restrict__ out)
{
  const long i = ((long)blockIdx.x * 256 + threadIdx.x) * 4;
  const int row = (int)(i >> 10), col = (int)(i & 1023);
  const int4 m = meta[row];
  const float2 w = wts[row];
  float4 a = *(const float4*)(xw + i);
  u16x4 p1 = *(const u16x4*)(part + (size_t)m.x * 1024 + col);
  u16x4 p2 = *(const u16x4*)(part + (size_t)m.y * 1024 + col);
  const float* b2a = b2 + m.z * 1024 + col;
  const float* b2b = b2 + m.w * 1024 + col;
  float av[4] = {a.x, a.y, a.z, a.w};
  float4 o;
  float ov[4];
#pragma unroll
  for (int j = 0; j < 4; j++)
    ov[j] = av[j] + h2f(p1[j]) + h2f(p2[j]) + w.x * b2a[j] + w.y * b2b[j];
  o.x = ov[0]; o.y = ov[1]; o.z = ov[2]; o.w = ov[3];
  *(float4*)(out + i) = o;
}

// ---------------------------------------------------------------------------
// f32 -> fp16 converters
// ---------------------------------------------------------------------------
__global__ __launch_bounds__(256)
void cvt_h(const float* __restrict__ src, u16* __restrict__ dst)
{
  const long i = ((long)blockIdx.x * 256 + threadIdx.x) * 4;
  float4 v = *(const float4*)(src + i);
  u16x4 o = {f2h(v.x), f2h(v.y), f2h(v.z), f2h(v.w)};
  *(u16x4*)(dst + i) = o;
}

__global__ __launch_bounds__(256)
void cvt_split(const float* __restrict__ src, u16* __restrict__ dh, u16* __restrict__ dl)
{
  const long i = ((long)blockIdx.x * 256 + threadIdx.x) * 4;
  float4 v = *(const float4*)(src + i);
  u16x4 oh, ol;
  float vv[4] = {v.x, v.y, v.z, v.w};
#pragma unroll
  for (int j = 0; j < 4; j++) { u16 a, b; split2(vv[j], a, b); oh[j] = a; ol[j] = b; }
  *(u16x4*)(dh + i) = oh;
  *(u16x4*)(dl + i) = ol;
}

struct Ptr8 { const float* p[8]; };

__global__ __launch_bounds__(256)
void cvt8_split(Ptr8 ps, u16* __restrict__ dh, u16* __restrict__ dl)
{
  const int w = blockIdx.y;
  const long i = ((long)blockIdx.x * 256 + threadIdx.x) * 4;
  float4 v = *(const float4*)(ps.p[w] + i);
  u16x4 oh, ol;
  float vv[4] = {v.x, v.y, v.z, v.w};
#pragma unroll
  for (int j = 0; j < 4; j++) { u16 a, b; split2(vv[j], a, b); oh[j] = a; ol[j] = b; }
  *(u16x4*)(dh + (long)w * 1048576 + i) = oh;
  *(u16x4*)(dl + (long)w * 1048576 + i) = ol;
}

// ---------------------------------------------------------------------------
extern "C" void kernel_launch(void* const* d_in, const int* in_sizes, int n_in,
                              void* d_out, int out_size, void* d_ws, size_t ws_size,
                              hipStream_t stream)
{
  const float* x    = (const float*)d_in[0];
  const float* mem  = (const float*)d_in[1];
  const float* sWq  = (const float*)d_in[2];
  const float* sWk  = (const float*)d_in[3];
  const float* sWv  = (const float*)d_in[4];
  const float* sWo  = (const float*)d_in[5];
  const float* cWq  = (const float*)d_in[6];
  const float* cWk  = (const float*)d_in[7];
  const float* cWv  = (const float*)d_in[8];
  const float* cWo  = (const float*)d_in[9];
  const float* Wg   = (const float*)d_in[10];
  const float* W1   = (const float*)d_in[11];
  const float* b1   = (const float*)d_in[12];
  const float* W2   = (const float*)d_in[13];
  const float* b2   = (const float*)d_in[14];
  const float* ln1g = (const float*)d_in[15];
  const float* ln1b = (const float*)d_in[16];
  const float* ln2g = (const float*)d_in[17];
  const float* ln2b = (const float*)d_in[18];
  const float* ln3g = (const float*)d_in[19];
  const float* ln3b = (const float*)d_in[20];
  float* out = (float*)d_out;
  (void)in_sizes; (void)n_in; (void)out_size; (void)ws_size;

  char* ws = (char*)d_ws;
  size_t off = 0;
  auto alloc = [&](size_t bytes) -> void* {
    void* p = ws + off; off += (bytes + 255) & ~(size_t)255; return p;
  };
  float* xw    = (float*)alloc((size_t)4096 * 1024 * 4);
  u16*   hh    = (u16*)  alloc((size_t)4096 * 1024 * 2);
  u16*   hl    = (u16*)  alloc((size_t)4096 * 1024 * 2);
  u16*   memh  = (u16*)  alloc((size_t)4096 * 1024 * 2);
  u16*   meml  = (u16*)  alloc((size_t)4096 * 1024 * 2);
  u16*   qkvh  = (u16*)  alloc((size_t)4096 * 3072 * 2);
  u16*   qkvl  = (u16*)  alloc((size_t)4096 * 3072 * 2);
  u16*   aoh   = (u16*)  alloc((size_t)4096 * 1024 * 2);
  u16*   aol   = (u16*)  alloc((size_t)4096 * 1024 * 2);
  u16*   vtH   = (u16*)  alloc((size_t)4096 * 1024 * 2);
  u16*   vtL   = (u16*)  alloc((size_t)4096 * 1024 * 2);
  u16*   aWh   = (u16*)  alloc((size_t)8 * 1024 * 1024 * 2);
  u16*   aWl   = (u16*)  alloc((size_t)8 * 1024 * 1024 * 2);
  u16*   w1h   = (u16*)  alloc((size_t)4 * 4096 * 1024 * 2);
  u16*   w2h   = (u16*)  alloc((size_t)4 * 4096 * 1024 * 2);
  float* glog  = (float*)alloc((size_t)4096 * 4 * 4);
  int*   tlist = (int*)  alloc((size_t)8704 * 4);
  float* wrow  = (float*)alloc((size_t)8704 * 4);
  int4*  meta  = (int4*) alloc((size_t)4096 * 16);
  float2* wts  = (float2*)alloc((size_t)4096 * 8);
  int*   scanM = (int*)  alloc((size_t)128 * 4);
  // reuse (dead regions):
  u16*   hid = qkvh;             // 8704*4096*2 = 71.3 MB <= qkvh..aWl region
  u16*   part = (u16*)hh;        // 8704*1024*2 = 17.8 MB <= hh..meml (32 MB)

  Ptr8 p8;
  p8.p[0] = sWq; p8.p[1] = sWk; p8.p[2] = sWv; p8.p[3] = sWo;
  p8.p[4] = cWq; p8.p[5] = cWk; p8.p[6] = cWv; p8.p[7] = cWo;
  cvt8_split<<<dim3(1024, 8), 256, 0, stream>>>(p8, aWh, aWl);
  cvt_h<<<16384, 256, 0, stream>>>(W1, w1h);
  cvt_h<<<16384, 256, 0, stream>>>(W2, w2h);
  cvt_split<<<4096, 256, 0, stream>>>(mem, memh, meml);

  // ---- self attention ----
  ln_kernel<false><<<4096, 256, 0, stream>>>(x, ln1g, ln1b, hh, hl, nullptr, nullptr);
  gemm3<EPI3_SPLIT><<<768, 512, 0, stream>>>(hh, hl, aWh, aWl, 24, 1024, 3072,
                                             qkvh, qkvl, nullptr, nullptr);
  vtrans<<<dim3(16, 16, 4), 256, 0, stream>>>(qkvh + 2048, qkvl + 2048, vtH, vtL);
  attn3<<<512, 512, 0, stream>>>(qkvh, qkvl, qkvh + 1024, qkvl + 1024,
                                 vtH, vtL, aoh, aol);
  gemm3<EPI3_RESID><<<256, 512, 0, stream>>>(aoh, aol, aWh + (size_t)3 * 1048576,
                                             aWl + (size_t)3 * 1048576, 8, 1024, 1024,
                                             nullptr, nullptr, xw, x);

  // ---- cross attention ----
  ln_kernel<false><<<4096, 256, 0, stream>>>(xw, ln2g, ln2b, hh, hl, nullptr, nullptr);
  gemm3<EPI3_SPLIT><<<256, 512, 0, stream>>>(hh, hl, aWh + (size_t)4 * 1048576,
                                             aWl + (size_t)4 * 1048576, 8, 1024, 3072,
                                             qkvh, qkvl, nullptr, nullptr);
  gemm3<EPI3_SPLIT><<<512, 512, 0, stream>>>(memh, meml, aWh + (size_t)5 * 1048576,
                                             aWl + (size_t)5 * 1048576, 16, 1024, 3072,
                                             qkvh + 1024, qkvl + 1024, nullptr, nullptr);
  vtrans<<<dim3(16, 16, 4), 256, 0, stream>>>(qkvh + 2048, qkvl + 2048, vtH, vtL);
  attn3<<<512, 512, 0, stream>>>(qkvh, qkvl, qkvh + 1024, qkvl + 1024,
                                 vtH, vtL, aoh, aol);
  gemm3<EPI3_RESID><<<256, 512, 0, stream>>>(aoh, aol, aWh + (size_t)7 * 1048576,
                                             aWl + (size_t)7 * 1048576, 8, 1024, 1024,
                                             nullptr, nullptr, xw, xw);

  // ---- MoE (sparse top-2, coef folded into hid') ----
  ln_kernel<true><<<4096, 256, 0, stream>>>(xw, ln3g, ln3b, hh, hl, Wg, glog);
  route_kernel<<<1, 256, 0, stream>>>(glog, tlist, wrow, meta, wts, scanM,
                                      out + (size_t)4096 * 1024);
  gemm_up<<<1088, 512, 0, stream>>>(hh, w1h, b1, tlist, wrow, scanM, hid);
  gemm_down<<<544, 512, 0, stream>>>(hid, w2h, scanM, part);
  merge_kernel<<<4096, 256, 0, stream>>>(xw, part, meta, wts, b2, out);
}

// Round 17
// 721.067 us; speedup vs baseline: 1.4278x; 1.4278x over previous
//
#include <hip/hip_runtime.h>
#include <math.h>
#include <stdint.h>

typedef unsigned short u16;
typedef _Float16 f16;
typedef __attribute__((ext_vector_type(8))) _Float16 f16x8;
typedef __attribute__((ext_vector_type(8))) short s16x8;
typedef __attribute__((ext_vector_type(4))) float f32x4;
typedef __attribute__((ext_vector_type(4))) unsigned short u16x4;

#define DEV static __device__ __forceinline__

#define MFMA16(a, b, c) __builtin_amdgcn_mfma_f32_16x16x32_f16((a), (b), (c), 0, 0, 0)

// split f32 into hi+lo fp16 (residual rel ~2^-22)
DEV void split2(float v, u16& hi, u16& lo) {
  f16 h = (f16)v;
  f16 l = (f16)(v - (float)h);
  hi = __builtin_bit_cast(u16, h);
  lo = __builtin_bit_cast(u16, l);
}
DEV u16 f2h(float v) { f16 h = (f16)v; return __builtin_bit_cast(u16, h); }
DEV float h2f(u16 u) { f16 h = __builtin_bit_cast(f16, u); return (float)h; }

DEV void gload16(const void* gp, const void* lp) {
  typedef const __attribute__((address_space(1))) unsigned GU;
  typedef __attribute__((address_space(3))) unsigned LU;
  GU* g = (GU*)(uintptr_t)gp;
  LU* l = (LU*)(unsigned)(uintptr_t)lp;
  __builtin_amdgcn_global_load_lds(g, l, 16, 0, 0);
}

// P-plane LDS swizzle: write q-rows conflict-free, read rows 2-way
DEV int swzP(int q) { return ((q & 3) << 4) ^ (((q >> 2) & 3) << 5); }

// GEMM tile chunk swizzle: 16B-chunk c of row r stored at chunk c^((r>>1)&3).
// Staged via pre-swizzled GLOBAL source col (gload_lds dest stays linear);
// read via XOR on the k-chunk index. 8-way -> 2-way bank aliasing (free).

// ---------------------------------------------------------------------------
// Emulated-f32 GEMM: C = (Ah+Al)*(Bh+Bl)^T, 3-term MFMA (ll dropped, ~1e-7).
// 128x128 tile, BK=32, 8 waves. Double-buffered prefetch K-loop.
// 1D grid, XCD-chunked by ROW (A-panel L2-resident); grid = 32*nColT.
// ---------------------------------------------------------------------------
enum { EPI3_SPLIT = 0, EPI3_RESID = 1 };

template <int EPI>
__global__ __launch_bounds__(512, 4)
void gemm3(const u16* __restrict__ Ah, const u16* __restrict__ Al,
           const u16* __restrict__ Bh, const u16* __restrict__ Bl,
           int nColT, int K, int ldC,
           u16* __restrict__ outh, u16* __restrict__ outl,
           float* __restrict__ outf, const float* __restrict__ resid)
{
  __shared__ alignas(16) u16 sAh[2][128 * 32], sAl[2][128 * 32];
  __shared__ alignas(16) u16 sBh[2][128 * 32], sBl[2][128 * 32];
  const int L = blockIdx.x;
  const int s = L >> 3;
  const int rt = (L & 7) * 4 + s / nColT;    // 4 row-tiles per XCD (32 total)
  const int ct = s % nColT;
  const int tid = threadIdx.x;
  const int wave = tid >> 6, lane = tid & 63;
  const int wr = wave >> 2, wc = wave & 3;      // 2x4 waves, 64x32 tile each
  const int li = lane & 15, g = lane >> 4;
  const long row0 = (long)rt * 128;
  const int col0 = ct * 128;

  const int srow = tid >> 2;                    // 0..127
  const int scol = ((tid & 3) ^ ((tid >> 3) & 3)) * 8;   // swizzled source chunk
  const long arow = (row0 + srow) * (long)K + scol;
  const long brow = ((long)col0 + srow) * (long)K + scol;
  const u16 *gAh = Ah + arow, *gAl = Al + arow;
  const u16 *gBh = Bh + brow, *gBl = Bl + brow;
  const int wbase = wave * 512;                 // wave-uniform LDS base (elems)

  const f32x4 fz = {0.f, 0.f, 0.f, 0.f};
  f32x4 acc[4][2];
#pragma unroll
  for (int m = 0; m < 4; m++)
#pragma unroll
    for (int n = 0; n < 2; n++) acc[m][n] = fz;

  const int aoff = (wr * 64 + li) * 32 + (g ^ ((li >> 1) & 3)) * 8;
  const int boff = (wc * 32 + li) * 32 + (g ^ ((li >> 1) & 3)) * 8;

  // prologue: stage k0=0 into buf 0
  gload16(gAh, &sAh[0][wbase]);
  gload16(gAl, &sAl[0][wbase]);
  gload16(gBh, &sBh[0][wbase]);
  gload16(gBl, &sBl[0][wbase]);

  int cur = 0;
  for (int k0 = 0; k0 < K; k0 += 32, cur ^= 1) {
    __syncthreads();   // buf[cur] staged (implicit vmcnt drain); buf[nxt] free
    const int nxt = cur ^ 1;
    if (k0 + 32 < K) {
      gload16(gAh + k0 + 32, &sAh[nxt][wbase]);
      gload16(gAl + k0 + 32, &sAl[nxt][wbase]);
      gload16(gBh + k0 + 32, &sBh[nxt][wbase]);
      gload16(gBl + k0 + 32, &sBl[nxt][wbase]);
    }
    f16x8 ah[4], al4[4], bh[2], bl4[2];
#pragma unroll
    for (int m = 0; m < 4; m++) {
      ah[m] = *(const f16x8*)(&sAh[cur][aoff + m * 512]);
      al4[m] = *(const f16x8*)(&sAl[cur][aoff + m * 512]);
    }
#pragma unroll
    for (int n = 0; n < 2; n++) {
      bh[n] = *(const f16x8*)(&sBh[cur][boff + n * 512]);
      bl4[n] = *(const f16x8*)(&sBl[cur][boff + n * 512]);
    }
#pragma unroll
    for (int m = 0; m < 4; m++)
#pragma unroll
      for (int n = 0; n < 2; n++) {
        f32x4 t = acc[m][n];
        t = MFMA16(al4[m], bh[n], t);
        t = MFMA16(ah[m], bl4[n], t);
        t = MFMA16(ah[m], bh[n], t);
        acc[m][n] = t;
      }
  }

#pragma unroll
  for (int m = 0; m < 4; m++)
#pragma unroll
    for (int n = 0; n < 2; n++) {
      const int col = col0 + wc * 32 + n * 16 + li;
#pragma unroll
      for (int r = 0; r < 4; r++) {
        const long row = row0 + wr * 64 + m * 16 + g * 4 + r;
        const long idx = row * ldC + col;
        const float v = acc[m][n][r];
        if constexpr (EPI == EPI3_SPLIT) {
          u16 hi, lo; split2(v, hi, lo);
          outh[idx] = hi; outl[idx] = lo;
        } else {
          outf[idx] = resid[idx] + v;
        }
      }
    }
}

// ---------------------------------------------------------------------------
// V transpose: [4096 rows=(b,key)][ld 3072] (cols h*64+dh) -> Vt[(b*16+h)*64+dh][1024 keys]
// ---------------------------------------------------------------------------
__global__ __launch_bounds__(256)
void vtrans(const u16* __restrict__ Vh, const u16* __restrict__ Vl,
            u16* __restrict__ Th, u16* __restrict__ Tl)
{
  __shared__ u16 t0[64][80];
  __shared__ u16 t1[64][80];
  const int kb = blockIdx.x, h = blockIdx.y, b = blockIdx.z;
  const int tid = threadIdx.x;
  const int r = tid >> 2;        // 0..63 key row
  const int c = tid & 3;         // chunk
  const long srow = ((long)b * 1024 + kb * 64 + r) * 3072 + h * 64;
  s16x8 a0 = *(const s16x8*)(Vh + srow + c * 8);
  s16x8 a1 = *(const s16x8*)(Vh + srow + c * 8 + 32);
  s16x8 b0 = *(const s16x8*)(Vl + srow + c * 8);
  s16x8 b1 = *(const s16x8*)(Vl + srow + c * 8 + 32);
#pragma unroll
  for (int j = 0; j < 8; j++) {
    t0[c * 8 + j][r]      = (u16)(short)a0[j];
    t0[c * 8 + 32 + j][r] = (u16)(short)a1[j];
    t1[c * 8 + j][r]      = (u16)(short)b0[j];
    t1[c * 8 + 32 + j][r] = (u16)(short)b1[j];
  }
  __syncthreads();
  const int dh = tid >> 2;
  const long drow = ((long)(b * 16 + h) * 64 + dh) * 1024 + kb * 64;
  s16x8 o0, o1;
#pragma unroll
  for (int j = 0; j < 8; j++) {
    o0[j] = (short)t0[dh][c * 8 + j];
    o1[j] = (short)t0[dh][c * 8 + 32 + j];
  }
  *(s16x8*)(Th + drow + c * 8) = o0;
  *(s16x8*)(Th + drow + c * 8 + 32) = o1;
#pragma unroll
  for (int j = 0; j < 8; j++) {
    o0[j] = (short)t1[dh][c * 8 + j];
    o1[j] = (short)t1[dh][c * 8 + 32 + j];
  }
  *(s16x8*)(Tl + drow + c * 8) = o0;
  *(s16x8*)(Tl + drow + c * 8 + 32) = o1;
}

// ---------------------------------------------------------------------------
// Flash attention, emulated-f32 (3-term MFMA). V pre-transposed.
// QBLK=128, 8 waves x 16 q-rows. XCD-chunked grid (512).
// Row-sum l computed via ones-MFMA fused with PV (no shfl-sum).
// ---------------------------------------------------------------------------
__global__ __launch_bounds__(512, 4)
void attn3(const u16* __restrict__ Qh, const u16* __restrict__ Ql,
           const u16* __restrict__ Kbh, const u16* __restrict__ Kbl,
           const u16* __restrict__ Vth, const u16* __restrict__ Vtl,
           u16* __restrict__ AOh, u16* __restrict__ AOl)
{
  __shared__ alignas(16) u16 lKh[64 * 64], lKl[64 * 64];
  __shared__ alignas(16) u16 lVh[64 * 64], lVl[64 * 64];   // [dh][key], swizzled
  __shared__ alignas(16) u16 lPh[8 * 16 * 64], lPl[8 * 16 * 64];
  const int L = blockIdx.x;
  const int idx = L >> 3;
  const int qt = idx & 7;                  // q-tile contiguous within XCD
  const int bhp = (L & 7) * 8 + (idx >> 3);
  const int b = bhp >> 4, h = bhp & 15;
  const int tid = threadIdx.x;
  const int wave = tid >> 6, lane = tid & 63;
  const int li = lane & 15, g = lane >> 4;
  const int bh = b * 16 + h;
  const int LD = 3072;

  const long qrow0 = (long)b * 1024 + qt * 128 + wave * 16;
  f16x8 qfh[2], qfl[2];
#pragma unroll
  for (int kk = 0; kk < 2; kk++) {
    const long qoff = (qrow0 + li) * LD + h * 64 + kk * 32 + g * 8;
    qfh[kk] = *(const f16x8*)(Qh + qoff);
    qfl[kk] = *(const f16x8*)(Ql + qoff);
  }

  const f32x4 fz = {0.f, 0.f, 0.f, 0.f};
  f16x8 one8;
#pragma unroll
  for (int j = 0; j < 8; j++) one8[j] = (f16)1.f;
  float m_run[4];
  f32x4 lsum = fz;
  f32x4 oacc[4];
#pragma unroll
  for (int r = 0; r < 4; r++) m_run[r] = -INFINITY;
#pragma unroll
  for (int d = 0; d < 4; d++) oacc[d] = fz;

  char* cKh = (char*)lKh; char* cKl = (char*)lKl;
  char* cVh = (char*)lVh; char* cVl = (char*)lVl;
  char* cPh = (char*)lPh + wave * 2048;
  char* cPl = (char*)lPl + wave * 2048;

  const int kr = tid >> 3;              // 0..63
  const int kce = (tid & 7) * 8;
  const u16* kbase_h = Kbh + ((long)b * 1024 + kr) * LD + h * 64 + kce;
  const u16* kbase_l = Kbl + ((long)b * 1024 + kr) * LD + h * 64 + kce;
  const u16* vbase_h = Vth + ((long)bh * 64 + kr) * 1024 + kce;
  const u16* vbase_l = Vtl + ((long)bh * 64 + kr) * 1024 + kce;
  const int sdst = kr * 128 + ((kce * 2) ^ ((kr & 7) << 4));

  s16x8 rkh, rkl, rvh, rvl;
#define LOADT(t)                                                   \
  {                                                                \
    const long ko = (long)(t) * 64 * LD;                           \
    const int vo = (t) * 64;                                       \
    rkh = *(const s16x8*)(kbase_h + ko);                           \
    rkl = *(const s16x8*)(kbase_l + ko);                           \
    rvh = *(const s16x8*)(vbase_h + vo);                           \
    rvl = *(const s16x8*)(vbase_l + vo);                           \
  }

  LOADT(0);

  for (int t = 0; t < 16; ++t) {
    __syncthreads();
    *(s16x8*)(cKh + sdst) = rkh;
    *(s16x8*)(cKl + sdst) = rkl;
    *(s16x8*)(cVh + sdst) = rvh;
    *(s16x8*)(cVl + sdst) = rvl;
    if (t < 15) LOADT(t + 1);
    __syncthreads();

    f32x4 s[4];
#pragma unroll
    for (int cb = 0; cb < 4; cb++) {
      f32x4 tt = fz;
      const int key = cb * 16 + li;
#pragma unroll
      for (int kk = 0; kk < 2; kk++) {
        const int off = key * 128 + (((kk * 32 + g * 8) * 2) ^ ((key & 7) << 4));
        f16x8 fh = *(const f16x8*)(cKh + off);
        f16x8 fl = *(const f16x8*)(cKl + off);
        tt = MFMA16(qfl[kk], fh, tt);
        tt = MFMA16(qfh[kk], fl, tt);
        tt = MFMA16(qfh[kk], fh, tt);
      }
      s[cb] = tt;
    }
#pragma unroll
    for (int cb = 0; cb < 4; cb++)
#pragma unroll
      for (int r = 0; r < 4; r++) s[cb][r] *= 0.125f;

    // online softmax: max via shfl; sum deferred to ones-MFMA in PV
#pragma unroll
    for (int r = 0; r < 4; r++) {
      float mx = fmaxf(fmaxf(s[0][r], s[1][r]), fmaxf(s[2][r], s[3][r]));
      mx = fmaxf(mx, __shfl_xor(mx, 1));
      mx = fmaxf(mx, __shfl_xor(mx, 2));
      mx = fmaxf(mx, __shfl_xor(mx, 4));
      mx = fmaxf(mx, __shfl_xor(mx, 8));
      float mnew = fmaxf(m_run[r], mx);
      float sc = __expf(m_run[r] - mnew);
      m_run[r] = mnew;
#pragma unroll
      for (int cb = 0; cb < 4; cb++) s[cb][r] = __expf(s[cb][r] - mnew);
      lsum[r] *= sc;
#pragma unroll
      for (int d = 0; d < 4; d++) oacc[d][r] *= sc;
    }

#pragma unroll
    for (int cb = 0; cb < 4; cb++)
#pragma unroll
      for (int r = 0; r < 4; r++) {
        const int q = g * 4 + r;
        const int key = cb * 16 + li;
        const int off = q * 128 + ((key * 2) ^ swzP(q));
        u16 hi, lo; split2(s[cb][r], hi, lo);
        *(u16*)(cPh + off) = hi;
        *(u16*)(cPl + off) = lo;
      }

#pragma unroll
    for (int kk = 0; kk < 2; kk++) {
      const int kbyte = (kk * 32 + g * 8) * 2;
      const int poff = li * 128 + (kbyte ^ swzP(li));
      f16x8 pfh = *(const f16x8*)(cPh + poff);
      f16x8 pfl = *(const f16x8*)(cPl + poff);
#pragma unroll
      for (int d = 0; d < 4; d++) {
        const int dh = d * 16 + li;
        const int voff = dh * 128 + (kbyte ^ ((dh & 7) << 4));
        f16x8 vfh = *(const f16x8*)(cVh + voff);
        f16x8 vfl = *(const f16x8*)(cVl + voff);
        f32x4 tacc = oacc[d];
        tacc = MFMA16(pfl, vfh, tacc);
        tacc = MFMA16(pfh, vfl, tacc);
        tacc = MFMA16(pfh, vfh, tacc);
        oacc[d] = tacc;
      }
      // row-sum of P via ones-B MFMA (every lane's r-elem = rowsum of q=g*4+r)
      lsum = MFMA16(pfh, one8, lsum);
      lsum = MFMA16(pfl, one8, lsum);
    }
  }
#undef LOADT

#pragma unroll
  for (int d = 0; d < 4; d++)
#pragma unroll
    for (int r = 0; r < 4; r++) {
      const long row = qrow0 + g * 4 + r;
      const int col = h * 64 + d * 16 + li;
      u16 hi, lo; split2(oacc[d][r] / lsum[r], hi, lo);
      AOh[row * 1024 + col] = hi;
      AOl[row * 1024 + col] = lo;
    }
}

// ---------------------------------------------------------------------------
// LayerNorm over D=1024 (one block/token) -> hi/lo fp16; optional f32 gate logits.
// ---------------------------------------------------------------------------
template <bool GATE>
__global__ __launch_bounds__(256)
void ln_kernel(const float* __restrict__ x, const float* __restrict__ gam,
               const float* __restrict__ bet, u16* __restrict__ hh,
               u16* __restrict__ hl,
               const float* __restrict__ Wg, float* __restrict__ glog)
{
  const int row = blockIdx.x;
  const int tid = threadIdx.x;
  const int wave = tid >> 6, lane = tid & 63;
  const float* xr = x + (long)row * 1024;
  float4 v = *(const float4*)(xr + tid * 4);
  float s = v.x + v.y + v.z + v.w;
  float s2 = v.x * v.x + v.y * v.y + v.z * v.z + v.w * v.w;
#pragma unroll
  for (int m = 1; m < 64; m <<= 1) { s += __shfl_xor(s, m); s2 += __shfl_xor(s2, m); }
  __shared__ float red1[4], red2[4];
  if (lane == 0) { red1[wave] = s; red2[wave] = s2; }
  __syncthreads();
  float S = red1[0] + red1[1] + red1[2] + red1[3];
  float S2 = red2[0] + red2[1] + red2[2] + red2[3];
  float mean = S * (1.f / 1024.f);
  float var = S2 * (1.f / 1024.f) - mean * mean;
  float rstd = 1.f / sqrtf(var + 1e-5f);
  const int c = tid * 4;
  float hv[4];
  hv[0] = (v.x - mean) * rstd * gam[c + 0] + bet[c + 0];
  hv[1] = (v.y - mean) * rstd * gam[c + 1] + bet[c + 1];
  hv[2] = (v.z - mean) * rstd * gam[c + 2] + bet[c + 2];
  hv[3] = (v.w - mean) * rstd * gam[c + 3] + bet[c + 3];
  u16x4 oh, ol;
#pragma unroll
  for (int j = 0; j < 4; j++) {
    u16 hi, lo; split2(hv[j], hi, lo);
    oh[j] = hi; ol[j] = lo;
  }
  *(u16x4*)(hh + (long)row * 1024 + c) = oh;
  *(u16x4*)(hl + (long)row * 1024 + c) = ol;

  if constexpr (GATE) {
    float pe[4];
#pragma unroll
    for (int e = 0; e < 4; e++) {
      const float* wr_ = Wg + e * 1024 + c;
      pe[e] = hv[0] * wr_[0] + hv[1] * wr_[1] + hv[2] * wr_[2] + hv[3] * wr_[3];
    }
#pragma unroll
    for (int e = 0; e < 4; e++)
#pragma unroll
      for (int m = 1; m < 64; m <<= 1) pe[e] += __shfl_xor(pe[e], m);
    __shared__ float gred[4][4];
    if (lane == 0) {
#pragma unroll
      for (int e = 0; e < 4; e++) gred[wave][e] = pe[e];
    }
    __syncthreads();
    if (tid < 4)
      glog[(long)row * 4 + tid] = gred[0][tid] + gred[1][tid] + gred[2][tid] + gred[3][tid];
  }
}

// ---------------------------------------------------------------------------
// Routing: top-2 + deterministic compaction (128-padded per-expert lists) + aux.
// ---------------------------------------------------------------------------
__global__ __launch_bounds__(256)
void route_kernel(const float* __restrict__ glog,
                  int* __restrict__ tlist, float* __restrict__ wrow,
                  int4* __restrict__ meta, float2* __restrict__ wts,
                  int* __restrict__ scanMeta, float* __restrict__ outAux)
{
  const int tid = threadIdx.x;
  const int lane = tid & 63, wave = tid >> 6;
  __shared__ int scn[4][256];
  __shared__ int sTot[4];
  __shared__ int sBase[4];
  __shared__ float sred[4][8];

  for (int r = tid; r < 8704; r += 256) { tlist[r] = 0; wrow[r] = 0.f; }

  int myCnt[4] = {0, 0, 0, 0};
  float imp[4] = {0.f, 0.f, 0.f, 0.f}, ld[4] = {0.f, 0.f, 0.f, 0.f};
  unsigned char e1s[16], e2s[16];
  float w1s[16], w2s[16];
#pragma unroll 1
  for (int j = 0; j < 16; j++) {
    const int t = tid * 16 + j;
    float l[4];
#pragma unroll
    for (int e = 0; e < 4; e++) l[e] = glog[t * 4 + e];
    int e1 = 0; float bv = l[0];
#pragma unroll
    for (int e = 1; e < 4; e++) if (l[e] > bv) { bv = l[e]; e1 = e; }
    int e2 = -1; float bv2 = -INFINITY;
#pragma unroll
    for (int e = 0; e < 4; e++) if (e != e1 && l[e] > bv2) { bv2 = l[e]; e2 = e; }
    float wq = expf(bv2 - bv);
    float w1 = 1.f / (1.f + wq), w2 = wq / (1.f + wq);
    float ps = 0.f, pv[4];
#pragma unroll
    for (int e = 0; e < 4; e++) { pv[e] = expf(l[e] - bv); ps += pv[e]; }
    float inv = 1.f / ps;
#pragma unroll
    for (int e = 0; e < 4; e++) imp[e] += pv[e] * inv;
    ld[e1] += 1.f; ld[e2] += 1.f;
    myCnt[e1]++; myCnt[e2]++;
    e1s[j] = (unsigned char)e1; e2s[j] = (unsigned char)e2;
    w1s[j] = w1; w2s[j] = w2;
  }
#pragma unroll
  for (int e = 0; e < 4; e++) scn[e][tid] = myCnt[e];
  __syncthreads();

  if (wave < 4) {
    int carry = 0;
    for (int seg = 0; seg < 4; seg++) {
      int v = scn[wave][seg * 64 + lane];
      const int orig = v;
#pragma unroll
      for (int d = 1; d < 64; d <<= 1) { int o = __shfl_up(v, d); if (lane >= d) v += o; }
      scn[wave][seg * 64 + lane] = carry + v - orig;
      carry += __shfl(v, 63);
    }
    if (lane == 0) sTot[wave] = carry;
  }
  __syncthreads();

  if (tid == 0) {
    int base = 0;
    for (int e = 0; e < 4; e++) {
      const int c = sTot[e];
      const int cap = (c + 127) & ~127;
      sBase[e] = base;
      const int t0 = base >> 7, t1 = (base + cap) >> 7;
      for (int i = t0; i < t1; i++) scanMeta[1 + i] = e;
      base += cap;
    }
    scanMeta[0] = base >> 7;
  }
  __syncthreads();

  int off[4];
#pragma unroll
  for (int e = 0; e < 4; e++) off[e] = sBase[e] + scn[e][tid];
#pragma unroll 1
  for (int j = 0; j < 16; j++) {
    const int t = tid * 16 + j;
    const int e1 = e1s[j], e2 = e2s[j];
    const int p1 = off[e1]++;
    const int p2 = off[e2]++;
    tlist[p1] = t; wrow[p1] = w1s[j];
    tlist[p2] = t; wrow[p2] = w2s[j];
    int4 m; m.x = p1; m.y = p2; m.z = e1; m.w = e2;
    meta[t] = m;
    float2 w; w.x = w1s[j]; w.y = w2s[j];
    wts[t] = w;
  }

#pragma unroll
  for (int e = 0; e < 4; e++) {
#pragma unroll
    for (int d = 1; d < 64; d <<= 1) {
      imp[e] += __shfl_xor(imp[e], d);
      ld[e] += __shfl_xor(ld[e], d);
    }
  }
  if (lane == 0) {
#pragma unroll
    for (int e = 0; e < 4; e++) { sred[wave][e] = imp[e]; sred[wave][4 + e] = ld[e]; }
  }
  __syncthreads();
  if (tid == 0) {
    float a = 0.f;
    for (int e = 0; e < 4; e++) {
      float im = sred[0][e] + sred[1][e] + sred[2][e] + sred[3][e];
      float lo = sred[0][4 + e] + sred[1][4 + e] + sred[2][4 + e] + sred[3][4 + e];
      a += (lo * (1.f / 4096.f)) * (im * (1.f / 4096.f));
    }
    outAux[0] = 0.01f * 4.f * a;
  }
}

// ---------------------------------------------------------------------------
// Sparse MoE up-proj: 128x256 tile, 512 thr / 8 waves (2x4, 64x64 wave tile).
// ROW-chunked XCD grid 1088 = 8 * 136 (r11/r14-measured best: 107 us).
// Dbuf prefetch K-loop. (512,4): do NOT raise — (512,6) spilled acc (r15).
// ---------------------------------------------------------------------------
__global__ __launch_bounds__(512, 4)
void gemm_up(const u16* __restrict__ A, const u16* __restrict__ w1h,
             const float* __restrict__ b1, const int* __restrict__ tlist,
             const float* __restrict__ wrow, const int* __restrict__ scanMeta,
             u16* __restrict__ hid)
{
  const int L = blockIdx.x;
  const int gg = (L & 7) * 136 + (L >> 3);
  const int rt = gg >> 4, ct = gg & 15;
  if (rt >= scanMeta[0]) return;
  const int e = scanMeta[1 + rt];
  __shared__ alignas(16) u16 lA[2][128 * 32];
  __shared__ alignas(16) u16 lB[2][256 * 32];
  const int tid = threadIdx.x;
  const int wave = tid >> 6, lane = tid & 63;
  const int wr = wave >> 2, wcn = wave & 3;   // 2x4 waves, 64x64 wave tile
  const int li = lane & 15, g = lane >> 4;
  const int row0 = rt * 128;
  const int col0 = ct * 256;

  const int srow = tid >> 2;                  // 0..127
  const int scol = ((tid & 3) ^ ((tid >> 3) & 3)) * 8;   // swizzled source chunk
  const long t1 = tlist[row0 + srow];
  const u16* gA1 = A + t1 * 1024 + scol;
  const u16* gB1 = w1h + (size_t)e * 4194304 +
                   ((size_t)(col0 + srow)) * 1024 + scol;
  const u16* gB2 = gB1 + (size_t)128 * 1024;
  const int wb = wave * 512;                  // wave-uniform LDS base (elems)

  const f32x4 fz = {0.f, 0.f, 0.f, 0.f};
  f32x4 acc[4][4];
#pragma unroll
  for (int m = 0; m < 4; m++)
#pragma unroll
    for (int n = 0; n < 4; n++) acc[m][n] = fz;

  const int aoff = (wr * 64 + li) * 32 + (g ^ ((li >> 1) & 3)) * 8;
  const int boff = (wcn * 64 + li) * 32 + (g ^ ((li >> 1) & 3)) * 8;

  // prologue
  gload16(gA1, &lA[0][wb]);
  gload16(gB1, &lB[0][wb]);
  gload16(gB2, &lB[0][4096 + wb]);

  int cur = 0;
  for (int k0 = 0; k0 < 1024; k0 += 32, cur ^= 1) {
    __syncthreads();
    const int nxt = cur ^ 1;
    if (k0 + 32 < 1024) {
      gload16(gA1 + k0 + 32, &lA[nxt][wb]);
      gload16(gB1 + k0 + 32, &lB[nxt][wb]);
      gload16(gB2 + k0 + 32, &lB[nxt][4096 + wb]);
    }
    f16x8 af[4], bfr[4];
#pragma unroll
    for (int m = 0; m < 4; m++) af[m] = *(const f16x8*)(&lA[cur][aoff + m * 512]);
#pragma unroll
    for (int n = 0; n < 4; n++) bfr[n] = *(const f16x8*)(&lB[cur][boff + n * 512]);
#pragma unroll
    for (int m = 0; m < 4; m++)
#pragma unroll
      for (int n = 0; n < 4; n++)
        acc[m][n] = MFMA16(af[m], bfr[n], acc[m][n]);
  }

#pragma unroll
  for (int m = 0; m < 4; m++)
#pragma unroll
    for (int n = 0; n < 4; n++) {
      const int col = col0 + wcn * 64 + n * 16 + li;
#pragma unroll
      for (int r = 0; r < 4; r++) {
        const int row = row0 + wr * 64 + m * 16 + g * 4 + r;
        const float coef = wrow[row];
        float tv = acc[m][n][r] + b1[e * 4096 + col];
        float z = 1.59576912f * tv * (1.f + 0.044715f * tv * tv);
        float ge = tv / (1.f + __expf(-z));
        hid[(size_t)row * 4096 + col] = f2h(coef * ge);
      }
    }
}

// ---------------------------------------------------------------------------
// Sparse MoE down-proj -> fp16 partials. ROW-chunked XCD mapping (r6-proven:
// A row-tile 1 MB L2-resident across the 8 col-tiles; FETCH ~71 MB). (512,4).
// ---------------------------------------------------------------------------
__global__ __launch_bounds__(512, 4)
void gemm_down(const u16* __restrict__ hid, const u16* __restrict__ w2h,
               const int* __restrict__ scanMeta, u16* __restrict__ part)
{
  const int L = blockIdx.x;
  const int gg = (L & 7) * 68 + (L >> 3);
  const int rt = gg >> 3, cc = gg & 7;
  if (rt >= scanMeta[0]) return;
  const int e = scanMeta[1 + rt];
  __shared__ alignas(16) u16 lA[2][128 * 32];
  __shared__ alignas(16) u16 lB[2][128 * 32];
  const int tid = threadIdx.x;
  const int wave = tid >> 6, lane = tid & 63;
  const int wr = wave >> 2, wc = wave & 3;
  const int li = lane & 15, g = lane >> 4;
  const int row0 = rt * 128;
  const int col0 = cc * 128;

  const int srow = tid >> 2;           // 0..127
  const int scol = ((tid & 3) ^ ((tid >> 3) & 3)) * 8;   // swizzled source chunk
  const u16* gA = hid + ((size_t)(row0 + srow)) * 4096 + scol;
  const u16* gB = w2h + (size_t)e * 4194304 +
                  ((size_t)(col0 + srow)) * 4096 + scol;
  const int wbase = wave * 512;

  const f32x4 fz = {0.f, 0.f, 0.f, 0.f};
  f32x4 acc[4][2];
#pragma unroll
  for (int m = 0; m < 4; m++)
#pragma unroll
    for (int n = 0; n < 2; n++) acc[m][n] = fz;

  const int aoff = (wr * 64 + li) * 32 + (g ^ ((li >> 1) & 3)) * 8;
  const int boff = (wc * 32 + li) * 32 + (g ^ ((li >> 1) & 3)) * 8;

  // prologue
  gload16(gA, &lA[0][wbase]);
  gload16(gB, &lB[0][wbase]);

  int cur = 0;
  for (int k0 = 0; k0 < 4096; k0 += 32, cur ^= 1) {
    __syncthreads();
    const int nxt = cur ^ 1;
    if (k0 + 32 < 4096) {
      gload16(gA + k0 + 32, &lA[nxt][wbase]);
      gload16(gB + k0 + 32, &lB[nxt][wbase]);
    }
    f16x8 af[4], bfr[2];
#pragma unroll
    for (int m = 0; m < 4; m++) af[m] = *(const f16x8*)(&lA[cur][aoff + m * 512]);
#pragma unroll
    for (int n = 0; n < 2; n++) bfr[n] = *(const f16x8*)(&lB[cur][boff + n * 512]);
#pragma unroll
    for (int m = 0; m < 4; m++)
#pragma unroll
      for (int n = 0; n < 2; n++)
        acc[m][n] = MFMA16(af[m], bfr[n], acc[m][n]);
  }

#pragma unroll
  for (int m = 0; m < 4; m++)
#pragma unroll
    for (int n = 0; n < 2; n++) {
      const int col = col0 + wc * 32 + n * 16 + li;
#pragma unroll
      for (int r = 0; r < 4; r++) {
        const int row = row0 + wr * 64 + m * 16 + g * 4 + r;
        part[(size_t)row * 1024 + col] = f2h(acc[m][n][r]);
      }
    }
}

// ---------------------------------------------------------------------------
// Merge: out = xw + part[p1] + part[p2] + w1*b2[e1] + w2*b2[e2]
// ---------------------------------------------------------------------------
__global__ __launch_bounds__(256)
void merge_kernel(const float* __restrict__ xw, const u16* __restrict__ part,
                  const int4* __restrict__ meta, const float2* __restrict__ wts,
                  const float* __restrict__ b2, float* __restrict__ out)
{
  const long i = ((long)blockIdx.x * 256 + threadIdx.x) * 4;
  const int row = (int)(i >> 10), col = (int)(i & 1023);
  const int4 m = meta[row];
  const float2 w = wts[row];
  float4 a = *(const float4*)(xw + i);
  u16x4 p1 = *(const u16x4*)(part + (size_t)m.x * 1024 + col);
  u16x4 p2 = *(const u16x4*)(part + (size_t)m.y * 1024 + col);
  const float* b2a = b2 + m.z * 1024 + col;
  const float* b2b = b2 + m.w * 1024 + col;
  float av[4] = {a.x, a.y, a.z, a.w};
  float4 o;
  float ov[4];
#pragma unroll
  for (int j = 0; j < 4; j++)
    ov[j] = av[j] + h2f(p1[j]) + h2f(p2[j]) + w.x * b2a[j] + w.y * b2b[j];
  o.x = ov[0]; o.y = ov[1]; o.z = ov[2]; o.w = ov[3];
  *(float4*)(out + i) = o;
}

// ---------------------------------------------------------------------------
// f32 -> fp16 converters
// ---------------------------------------------------------------------------
__global__ __launch_bounds__(256)
void cvt_h(const float* __restrict__ src, u16* __restrict__ dst)
{
  const long i = ((long)blockIdx.x * 256 + threadIdx.x) * 4;
  float4 v = *(const float4*)(src + i);
  u16x4 o = {f2h(v.x), f2h(v.y), f2h(v.z), f2h(v.w)};
  *(u16x4*)(dst + i) = o;
}

__global__ __launch_bounds__(256)
void cvt_split(const float* __restrict__ src, u16* __restrict__ dh, u16* __restrict__ dl)
{
  const long i = ((long)blockIdx.x * 256 + threadIdx.x) * 4;
  float4 v = *(const float4*)(src + i);
  u16x4 oh, ol;
  float vv[4] = {v.x, v.y, v.z, v.w};
#pragma unroll
  for (int j = 0; j < 4; j++) { u16 a, b; split2(vv[j], a, b); oh[j] = a; ol[j] = b; }
  *(u16x4*)(dh + i) = oh;
  *(u16x4*)(dl + i) = ol;
}

struct Ptr8 { const float* p[8]; };

__global__ __launch_bounds__(256)
void cvt8_split(Ptr8 ps, u16* __restrict__ dh, u16* __restrict__ dl)
{
  const int w = blockIdx.y;
  const long i = ((long)blockIdx.x * 256 + threadIdx.x) * 4;
  float4 v = *(const float4*)(ps.p[w] + i);
  u16x4 oh, ol;
  float vv[4] = {v.x, v.y, v.z, v.w};
#pragma unroll
  for (int j = 0; j < 4; j++) { u16 a, b; split2(vv[j], a, b); oh[j] = a; ol[j] = b; }
  *(u16x4*)(dh + (long)w * 1048576 + i) = oh;
  *(u16x4*)(dl + (long)w * 1048576 + i) = ol;
}

// ---------------------------------------------------------------------------
extern "C" void kernel_launch(void* const* d_in, const int* in_sizes, int n_in,
                              void* d_out, int out_size, void* d_ws, size_t ws_size,
                              hipStream_t stream)
{
  const float* x    = (const float*)d_in[0];
  const float* mem  = (const float*)d_in[1];
  const float* sWq  = (const float*)d_in[2];
  const float* sWk  = (const float*)d_in[3];
  const float* sWv  = (const float*)d_in[4];
  const float* sWo  = (const float*)d_in[5];
  const float* cWq  = (const float*)d_in[6];
  const float* cWk  = (const float*)d_in[7];
  const float* cWv  = (const float*)d_in[8];
  const float* cWo  = (const float*)d_in[9];
  const float* Wg   = (const float*)d_in[10];
  const float* W1   = (const float*)d_in[11];
  const float* b1   = (const float*)d_in[12];
  const float* W2   = (const float*)d_in[13];
  const float* b2   = (const float*)d_in[14];
  const float* ln1g = (const float*)d_in[15];
  const float* ln1b = (const float*)d_in[16];
  const float* ln2g = (const float*)d_in[17];
  const float* ln2b = (const float*)d_in[18];
  const float* ln3g = (const float*)d_in[19];
  const float* ln3b = (const float*)d_in[20];
  float* out = (float*)d_out;
  (void)in_sizes; (void)n_in; (void)out_size; (void)ws_size;

  char* ws = (char*)d_ws;
  size_t off = 0;
  auto alloc = [&](size_t bytes) -> void* {
    void* p = ws + off; off += (bytes + 255) & ~(size_t)255; return p;
  };
  float* xw    = (float*)alloc((size_t)4096 * 1024 * 4);
  u16*   hh    = (u16*)  alloc((size_t)4096 * 1024 * 2);
  u16*   hl    = (u16*)  alloc((size_t)4096 * 1024 * 2);
  u16*   memh  = (u16*)  alloc((size_t)4096 * 1024 * 2);
  u16*   meml  = (u16*)  alloc((size_t)4096 * 1024 * 2);
  u16*   qkvh  = (u16*)  alloc((size_t)4096 * 3072 * 2);
  u16*   qkvl  = (u16*)  alloc((size_t)4096 * 3072 * 2);
  u16*   aoh   = (u16*)  alloc((size_t)4096 * 1024 * 2);
  u16*   aol   = (u16*)  alloc((size_t)4096 * 1024 * 2);
  u16*   vtH   = (u16*)  alloc((size_t)4096 * 1024 * 2);
  u16*   vtL   = (u16*)  alloc((size_t)4096 * 1024 * 2);
  u16*   aWh   = (u16*)  alloc((size_t)8 * 1024 * 1024 * 2);
  u16*   aWl   = (u16*)  alloc((size_t)8 * 1024 * 1024 * 2);
  u16*   w1h   = (u16*)  alloc((size_t)4 * 4096 * 1024 * 2);
  u16*   w2h   = (u16*)  alloc((size_t)4 * 4096 * 1024 * 2);
  float* glog  = (float*)alloc((size_t)4096 * 4 * 4);
  int*   tlist = (int*)  alloc((size_t)8704 * 4);
  float* wrow  = (float*)alloc((size_t)8704 * 4);
  int4*  meta  = (int4*) alloc((size_t)4096 * 16);
  float2* wts  = (float2*)alloc((size_t)4096 * 8);
  int*   scanM = (int*)  alloc((size_t)128 * 4);
  // reuse (dead regions):
  u16*   hid = qkvh;             // 8704*4096*2 = 71.3 MB <= qkvh..aWl region
  u16*   part = (u16*)hh;        // 8704*1024*2 = 17.8 MB <= hh..meml (32 MB)

  Ptr8 p8;
  p8.p[0] = sWq; p8.p[1] = sWk; p8.p[2] = sWv; p8.p[3] = sWo;
  p8.p[4] = cWq; p8.p[5] = cWk; p8.p[6] = cWv; p8.p[7] = cWo;
  cvt8_split<<<dim3(1024, 8), 256, 0, stream>>>(p8, aWh, aWl);
  cvt_h<<<16384, 256, 0, stream>>>(W1, w1h);
  cvt_h<<<16384, 256, 0, stream>>>(W2, w2h);
  cvt_split<<<4096, 256, 0, stream>>>(mem, memh, meml);

  // ---- self attention ----
  ln_kernel<false><<<4096, 256, 0, stream>>>(x, ln1g, ln1b, hh, hl, nullptr, nullptr);
  gemm3<EPI3_SPLIT><<<768, 512, 0, stream>>>(hh, hl, aWh, aWl, 24, 1024, 3072,
                                             qkvh, qkvl, nullptr, nullptr);
  vtrans<<<dim3(16, 16, 4), 256, 0, stream>>>(qkvh + 2048, qkvl + 2048, vtH, vtL);
  attn3<<<512, 512, 0, stream>>>(qkvh, qkvl, qkvh + 1024, qkvl + 1024,
                                 vtH, vtL, aoh, aol);
  gemm3<EPI3_RESID><<<256, 512, 0, stream>>>(aoh, aol, aWh + (size_t)3 * 1048576,
                                             aWl + (size_t)3 * 1048576, 8, 1024, 1024,
                                             nullptr, nullptr, xw, x);

  // ---- cross attention ----
  ln_kernel<false><<<4096, 256, 0, stream>>>(xw, ln2g, ln2b, hh, hl, nullptr, nullptr);
  gemm3<EPI3_SPLIT><<<256, 512, 0, stream>>>(hh, hl, aWh + (size_t)4 * 1048576,
                                             aWl + (size_t)4 * 1048576, 8, 1024, 3072,
                                             qkvh, qkvl, nullptr, nullptr);
  gemm3<EPI3_SPLIT><<<512, 512, 0, stream>>>(memh, meml, aWh + (size_t)5 * 1048576,
                                             aWl + (size_t)5 * 1048576, 16, 1024, 3072,
                                             qkvh + 1024, qkvl + 1024, nullptr, nullptr);
  vtrans<<<dim3(16, 16, 4), 256, 0, stream>>>(qkvh + 2048, qkvl + 2048, vtH, vtL);
  attn3<<<512, 512, 0, stream>>>(qkvh, qkvl, qkvh + 1024, qkvl + 1024,
                                 vtH, vtL, aoh, aol);
  gemm3<EPI3_RESID><<<256, 512, 0, stream>>>(aoh, aol, aWh + (size_t)7 * 1048576,
                                             aWl + (size_t)7 * 1048576, 8, 1024, 1024,
                                             nullptr, nullptr, xw, xw);

  // ---- MoE (sparse top-2, coef folded into hid') ----
  ln_kernel<true><<<4096, 256, 0, stream>>>(xw, ln3g, ln3b, hh, hl, Wg, glog);
  route_kernel<<<1, 256, 0, stream>>>(glog, tlist, wrow, meta, wts, scanM,
                                      out + (size_t)4096 * 1024);
  gemm_up<<<1088, 512, 0, stream>>>(hh, w1h, b1, tlist, wrow, scanM, hid);
  gemm_down<<<544, 512, 0, stream>>>(hid, w2h, scanM, part);
  merge_kernel<<<4096, 256, 0, stream>>>(xw, part, meta, wts, b2, out);
}